// Round 2
// baseline (978.056 us; speedup 1.0000x reference)
//
#include <hip/hip_runtime.h>
#include <hip/hip_bf16.h>

#define NTOK 8192
#define DDIM 1024
#define HDIM 4096
#define NEXP 8
#define NPAIR (NTOK * 2)
#define NMTILE 136          // 16384/128 + up to 8 per-expert pad tiles (128-row granularity)
#define NPADROW (NPAIR + NEXP * 128)

typedef __attribute__((ext_vector_type(8))) short short8;
typedef __attribute__((ext_vector_type(4))) float floatx4;

__device__ __forceinline__ unsigned short f2bf(float f) {
  unsigned u = __float_as_uint(f);
  u += 0x7fffu + ((u >> 16) & 1u);   // RNE
  return (unsigned short)(u >> 16);
}

__device__ __forceinline__ void async_copy16(const void* g, void* l) {
  __builtin_amdgcn_global_load_lds(
      (const __attribute__((address_space(1))) unsigned int*)g,
      (__attribute__((address_space(3))) unsigned int*)l, 16, 0, 0);
}

// ---------------- cast f32 -> bf16, float4 vectorized ----------------
__global__ void cast_kernel(const float* __restrict__ src,
                            unsigned short* __restrict__ dst, int n4) {
  int i = blockIdx.x * 256 + threadIdx.x;
  if (i >= n4) return;
  const float4 v = ((const float4*)src)[i];
  ushort4 o;
  o.x = f2bf(v.x); o.y = f2bf(v.y); o.z = f2bf(v.z); o.w = f2bf(v.w);
  ((ushort4*)dst)[i] = o;
}

// ---------------- gating: 1 wave per token, fp64 accumulation ----------------
__global__ __launch_bounds__(256) void gating_kernel(
    const float* __restrict__ x, const float* __restrict__ gw,
    int* __restrict__ selE, float* __restrict__ selW,
    int* __restrict__ cnt, float* __restrict__ psum) {
  __shared__ float gws[NEXP * DDIM];      // 32 KB
  __shared__ float pblk[4][NEXP];
  __shared__ int cblk[NEXP];
  const int t = threadIdx.x;
  for (int i = t; i < NEXP * DDIM; i += 256) gws[i] = gw[i];
  if (t < NEXP) cblk[t] = 0;
  __syncthreads();
  const int wv = t >> 6, lane = t & 63;
  const int tok = blockIdx.x * 4 + wv;
  double acc[NEXP];
#pragma unroll
  for (int e = 0; e < NEXP; e++) acc[e] = 0.0;
  const float* xr = x + (size_t)tok * DDIM;
  for (int i = lane; i < DDIM; i += 64) {
    double xv = (double)xr[i];
#pragma unroll
    for (int e = 0; e < NEXP; e++) acc[e] += xv * (double)gws[e * DDIM + i];
  }
#pragma unroll
  for (int e = 0; e < NEXP; e++)
    for (int off = 32; off > 0; off >>= 1) acc[e] += __shfl_xor(acc[e], off, 64);
  if (lane == 0) {
    double mx = acc[0];
    for (int e = 1; e < NEXP; e++) mx = acc[e] > mx ? acc[e] : mx;
    double p[NEXP], s = 0.0;
    for (int e = 0; e < NEXP; e++) { p[e] = exp(acc[e] - mx); s += p[e]; }
    int e1 = 0; double b1 = p[0];
    for (int e = 1; e < NEXP; e++) if (p[e] > b1) { b1 = p[e]; e1 = e; }
    int e2 = -1; double b2 = -1.0;
    for (int e = 0; e < NEXP; e++) if (e != e1 && p[e] > b2) { b2 = p[e]; e2 = e; }
    double rs = b1 + b2;
    selE[tok * 2 + 0] = e1; selE[tok * 2 + 1] = e2;
    selW[tok * 2 + 0] = (float)(b1 / rs); selW[tok * 2 + 1] = (float)(b2 / rs);
    atomicAdd(&cblk[e1], 1); atomicAdd(&cblk[e2], 1);
    for (int e = 0; e < NEXP; e++) pblk[wv][e] = (float)(p[e] / s);
  }
  __syncthreads();
  if (t < NEXP) {
    float sp = pblk[0][t] + pblk[1][t] + pblk[2][t] + pblk[3][t];
    atomicAdd(&psum[t], sp);
    if (cblk[t]) atomicAdd(&cnt[t], cblk[t]);
  }
}

// ---------------- prefix sums (128-aligned) + tile->expert table + balance loss ----------------
// Parallelized: the old 1-thread version did ~300 dependent global ops (tens of us).
__global__ __launch_bounds__(256) void finalize_kernel(
    const int* __restrict__ cnt, const float* __restrict__ psum,
    int* __restrict__ abase, int* __restrict__ fill,
    int* __restrict__ tile2exp, float* __restrict__ loss_out) {
  __shared__ int sb[NEXP + 1];
  __shared__ int scnt[NEXP];
  const int t = threadIdx.x;
  if (t == 0) {
    int b = 0;
    for (int e = 0; e < NEXP; e++) {
      int c = cnt[e];
      scnt[e] = c; sb[e] = b;
      b += ((c + 127) >> 7) << 7;
    }
    sb[NEXP] = b;
  }
  __syncthreads();
  if (t < NEXP) { abase[t] = sb[t]; fill[t] = sb[t]; }
  if (t == NEXP) abase[NEXP] = sb[NEXP];
  for (int i = t; i < NMTILE; i += 256) {
    int ex = -1;
#pragma unroll
    for (int e = 0; e < NEXP; e++) {
      int t0 = sb[e] >> 7, nt = (scnt[e] + 127) >> 7;
      if (i >= t0 && i < t0 + nt) ex = e;
    }
    tile2exp[i] = ex;
  }
  if (t == 0) {
    double L = 0.0;
    for (int e = 0; e < NEXP; e++) L += (double)psum[e] * (double)scnt[e];
    *loss_out = (float)(L * (double)NEXP / ((double)NTOK * (double)NTOK));
  }
}

// ---------------- scatter pairs: block-local histogram -> 1 global atomic per expert ----------------
__global__ __launch_bounds__(256) void scatter_kernel(
    const int* __restrict__ selE, const float* __restrict__ selW,
    int* __restrict__ fill, int* __restrict__ pairtok, float* __restrict__ pairw) {
  __shared__ int h1[NEXP], h2[NEXP], base[NEXP];
  const int t = threadIdx.x;
  if (t < NEXP) { h1[t] = 0; h2[t] = 0; }
  __syncthreads();
  const int n = blockIdx.x * 256 + t;
  const int e0 = selE[n * 2 + 0], e1 = selE[n * 2 + 1];
  atomicAdd(&h1[e0], 1); atomicAdd(&h1[e1], 1);
  __syncthreads();
  if (t < NEXP && h1[t]) base[t] = atomicAdd(&fill[t], h1[t]);
  __syncthreads();
  int r0 = atomicAdd(&h2[e0], 1);
  int p0 = base[e0] + r0;
  pairtok[p0] = n; pairw[p0] = selW[n * 2 + 0];
  int r1 = atomicAdd(&h2[e1], 1);
  int p1 = base[e1] + r1;
  pairtok[p1] = n; pairw[p1] = selW[n * 2 + 1];
}

// ---------------- MFMA GEMM, NT layout, pipelined (T3+T4) ----------------
// BM=128, BN=256, BK=32. 512 threads / 8 waves (2M x 4N), per-wave 64x64 output.
// LDS: 4-slot rotation (96 KB): compute kt from slot kt&3 while kt+1 is landed
// and kt+2 is in flight (prefetch distance 2 K-tiles ~ 1200 cyc > HBM latency).
// Raw s_barrier (NO __syncthreads -> no vmcnt(0) drain); counted s_waitcnt vmcnt(3)
// at each K-tile boundary; lgkmcnt(0) + setprio(1) around the 16-MFMA cluster.
// MODE 0: FC1  A = xb gathered via pairtok, epilogue relu^2 -> hbuf bf16
// MODE 1: FC2  A = hbuf padded-compact rows, epilogue atomicAdd w*y into out
template <int KD, int ND, int MODE>
__global__ __launch_bounds__(512, 1) void moe_gemm(
    const unsigned short* __restrict__ A, const unsigned short* __restrict__ B,
    const int* __restrict__ abase, const int* __restrict__ cnt,
    const int* __restrict__ tile2exp, const int* __restrict__ pairtok,
    const float* __restrict__ pairw, unsigned short* __restrict__ hbuf,
    float* __restrict__ out) {
  constexpr int NT = ND / 256;
  constexpr int KT = KD / 32;

  // XCD-chunked bijective swizzle (m204): kept -- it cut FETCH_SIZE 4.4x.
  const int nwg = NT * NMTILE;
  const int lid = blockIdx.y * NT + blockIdx.x;
  const int q8 = nwg >> 3, r8 = nwg & 7;
  const int xcd = lid & 7, sub = lid >> 3;
  const int cbase = (xcd < r8) ? xcd * (q8 + 1) : r8 * (q8 + 1) + (xcd - r8) * q8;
  const int nlid = cbase + sub;
  const int mtile = nlid / NT;
  const int ntile = nlid - mtile * NT;

  const int e = tile2exp[mtile];
  if (e < 0) return;
  const int m0 = abase[e];
  const int cntE = cnt[e];
  const int mloc = mtile * 128 - m0;

  __shared__ unsigned short ldsA[4][512 * 8];    // 4 slots x (128 rows x 32 k) = 32 KB
  __shared__ unsigned short ldsB[4][1024 * 8];   // 4 slots x (256 rows x 32 k) = 64 KB

  const int t = threadIdx.x, w = t >> 6, lane = t & 63;

  // ---- staging addresses (16B chunk c; chunk holds (row=c>>2, q=(c&3)^swz(row)))
  // A: 512 chunks, 1 per thread. B: 1024 chunks, 2 per thread.
  const int cA = t;
  const int rowA = cA >> 2;
  const int qA = (cA & 3) ^ (rowA & 3) ^ ((rowA >> 2) & 3);
  int ar = mloc + rowA;
  if (ar > cntE - 1) ar = cntE - 1;
  size_t arow;
  if (MODE == 0) arow = (size_t)pairtok[m0 + ar];
  else           arow = (size_t)(m0 + ar);
  const unsigned short* gA = A + arow * (size_t)KD + qA * 8;
  const int dstAoff = (w * 64) * 8;              // shorts, wave-uniform

  const unsigned short* gB[2];
  int dstBoff[2];
#pragma unroll
  for (int i = 0; i < 2; i++) {
    const int p = i * 512 + t;
    const int rowB = p >> 2;
    const int qB = (p & 3) ^ (rowB & 3) ^ ((rowB >> 2) & 3);
    gB[i] = B + ((size_t)e * ND + (ntile * 256 + rowB)) * (size_t)KD + qB * 8;
    dstBoff[i] = (i * 512 + w * 64) * 8;
  }

  // ---- fragment read positions (short8 units within one slot)
  const int wr = w >> 2, wc = w & 3;             // 2M x 4N wave grid
  const int sw = (lane >> 4) ^ (lane & 3) ^ ((lane >> 2) & 3);
  int apos[4], bpos[4];
#pragma unroll
  for (int i = 0; i < 4; i++) {
    apos[i] = (wr * 64 + i * 16 + (lane & 15)) * 4 + sw;
    bpos[i] = (wc * 64 + i * 16 + (lane & 15)) * 4 + sw;
  }

  floatx4 acc[4][4] = {};

  auto stage = [&](int kt2) {
    const int s = kt2 & 3;
    const int ko = kt2 * 32;
    async_copy16(gA + ko, &ldsA[s][dstAoff]);
    async_copy16(gB[0] + ko, &ldsB[s][dstBoff[0]]);
    async_copy16(gB[1] + ko, &ldsB[s][dstBoff[1]]);
  };

  // prologue: tiles 0 and 1 in flight; wait tile 0 (3 newest = tile 1 stay out)
  stage(0);
  stage(1);
  asm volatile("s_waitcnt vmcnt(3)" ::: "memory");
  __builtin_amdgcn_s_barrier();

#pragma unroll 4
  for (int kt = 0; kt < KT; ++kt) {
    const int s = kt & 3;
    short8 a[4], b[4];
#pragma unroll
    for (int i = 0; i < 4; i++) {
      a[i] = ((const short8*)ldsA[s])[apos[i]];
      b[i] = ((const short8*)ldsB[s])[bpos[i]];
    }
    if (kt + 2 < KT) stage(kt + 2);
    __builtin_amdgcn_s_barrier();                 // phase alignment (non-draining)
    asm volatile("s_waitcnt lgkmcnt(0)" ::: "memory");
    __builtin_amdgcn_s_setprio(1);
#pragma unroll
    for (int im = 0; im < 4; im++)
#pragma unroll
      for (int in = 0; in < 4; in++)
        acc[im][in] = __builtin_amdgcn_mfma_f32_16x16x32_bf16(a[im], b[in], acc[im][in], 0, 0, 0);
    __builtin_amdgcn_s_setprio(0);
    // boundary: tile kt+1 must be landed; tile kt+2 (3 loads) may stay in flight
    if (kt + 2 < KT) asm volatile("s_waitcnt vmcnt(3)" ::: "memory");
    else             asm volatile("s_waitcnt vmcnt(0)" ::: "memory");
    __builtin_amdgcn_s_barrier();
  }

  // epilogue: C/D layout row=(lane>>4)*4+r, col=lane&15 (m89/m91-verified)
  const int Mv = cntE - mloc;
#pragma unroll
  for (int im = 0; im < 4; im++) {
#pragma unroll
    for (int r = 0; r < 4; r++) {
      const int rl = wr * 64 + im * 16 + (lane >> 4) * 4 + r;
      if (rl < Mv) {
        const int pr = m0 + mloc + rl;
        if (MODE == 0) {
#pragma unroll
          for (int in = 0; in < 4; in++) {
            float v = acc[im][in][r];
            v = v > 0.f ? v * v : 0.f;   // relu^2
            const int col = ntile * 256 + wc * 64 + in * 16 + (lane & 15);
            hbuf[(size_t)pr * HDIM + col] = f2bf(v);
          }
        } else {
          const float wgt = pairw[pr];
          const int tok = pairtok[pr];
          float* yrow = out + (size_t)tok * DDIM;
#pragma unroll
          for (int in = 0; in < 4; in++) {
            const int col = ntile * 256 + wc * 64 + in * 16 + (lane & 15);
            atomicAdd(yrow + col, wgt * acc[im][in][r]);  // 2 addends/elem -> exact
          }
        }
      }
    }
  }
}

extern "C" void kernel_launch(void* const* d_in, const int* in_sizes, int n_in,
                              void* d_out, int out_size, void* d_ws, size_t ws_size,
                              hipStream_t stream) {
  const float* x   = (const float*)d_in[0];
  const float* gw  = (const float*)d_in[1];
  const float* wfc = (const float*)d_in[2];
  const float* wpj = (const float*)d_in[3];
  float* out = (float*)d_out;

  char* ws = (char*)d_ws;
  size_t off = 0;
  auto alloc = [&](size_t bytes) -> void* {
    void* p = ws + off;
    off += (bytes + 255) & ~(size_t)255;
    return p;
  };
  unsigned short* xb   = (unsigned short*)alloc((size_t)NTOK * DDIM * 2);
  unsigned short* wfcb = (unsigned short*)alloc((size_t)NEXP * HDIM * DDIM * 2);
  unsigned short* wpjb = (unsigned short*)alloc((size_t)NEXP * DDIM * HDIM * 2);
  unsigned short* hbuf = (unsigned short*)alloc((size_t)NPADROW * HDIM * 2);
  int*   pairtok = (int*)alloc(NPADROW * 4);
  float* pairw   = (float*)alloc(NPADROW * 4);
  int*   selE    = (int*)alloc(NTOK * 2 * 4);
  float* selW    = (float*)alloc(NTOK * 2 * 4);
  int*   ctr     = (int*)alloc(1024);
  int* cnt = ctr; int* fill = ctr + 8; int* abase = ctr + 16;   // abase: 9 ints
  float* psum = (float*)(ctr + 28);                              // 8 floats
  int* tile2exp = ctr + 40;                                      // 136 ints

  hipMemsetAsync(ctr, 0, 1024, stream);
  hipMemsetAsync(out, 0, (size_t)NTOK * DDIM * 4, stream);       // FC2 accumulates into out

  cast_kernel<<<(NTOK * DDIM / 4 + 255) / 256, 256, 0, stream>>>(x, xb, NTOK * DDIM / 4);
  cast_kernel<<<(NEXP * HDIM * DDIM / 4 + 255) / 256, 256, 0, stream>>>(wfc, wfcb, NEXP * HDIM * DDIM / 4);
  cast_kernel<<<(NEXP * DDIM * HDIM / 4 + 255) / 256, 256, 0, stream>>>(wpj, wpjb, NEXP * DDIM * HDIM / 4);

  gating_kernel<<<NTOK / 4, 256, 0, stream>>>(x, gw, selE, selW, cnt, psum);
  finalize_kernel<<<1, 256, 0, stream>>>(cnt, psum, abase, fill, tile2exp,
                                         out + (size_t)NTOK * DDIM);
  scatter_kernel<<<NTOK / 256, 256, 0, stream>>>(selE, selW, fill, pairtok, pairw);

  moe_gemm<DDIM, HDIM, 0><<<dim3(HDIM / 256, NMTILE), 512, 0, stream>>>(
      xb, wfcb, abase, cnt, tile2exp, pairtok, pairw, hbuf, nullptr);
  moe_gemm<HDIM, DDIM, 1><<<dim3(DDIM / 256, NMTILE), 512, 0, stream>>>(
      hbuf, wpjb, abase, cnt, tile2exp, pairtok, pairw, nullptr, out);
}

// Round 3
// 893.481 us; speedup vs baseline: 1.0947x; 1.0947x over previous
//
#include <hip/hip_runtime.h>
#include <hip/hip_bf16.h>

#define NTOK 8192
#define DDIM 1024
#define HDIM 4096
#define NEXP 8
#define NPAIR (NTOK * 2)
#define NMT 72              // 16384/256 + up to 8 per-expert pad tiles (256-row granularity)
#define NPADROW (NPAIR + NEXP * 256)

typedef __attribute__((ext_vector_type(8))) short short8;
typedef __attribute__((ext_vector_type(4))) float floatx4;

__device__ __forceinline__ unsigned short f2bf(float f) {
  unsigned u = __float_as_uint(f);
  u += 0x7fffu + ((u >> 16) & 1u);   // RNE
  return (unsigned short)(u >> 16);
}

__device__ __forceinline__ void async_copy16(const void* g, void* l) {
  __builtin_amdgcn_global_load_lds(
      (const __attribute__((address_space(1))) unsigned int*)g,
      (__attribute__((address_space(3))) unsigned int*)l, 16, 0, 0);
}

// ---------------- cast f32 -> bf16, float4 vectorized ----------------
__global__ void cast_kernel(const float* __restrict__ src,
                            unsigned short* __restrict__ dst, int n4) {
  int i = blockIdx.x * 256 + threadIdx.x;
  if (i >= n4) return;
  const float4 v = ((const float4*)src)[i];
  ushort4 o;
  o.x = f2bf(v.x); o.y = f2bf(v.y); o.z = f2bf(v.z); o.w = f2bf(v.w);
  ((ushort4*)dst)[i] = o;
}

// ---------------- gating: 1 wave per token, fp64 accumulation ----------------
__global__ __launch_bounds__(256) void gating_kernel(
    const float* __restrict__ x, const float* __restrict__ gw,
    int* __restrict__ selE, float* __restrict__ selW,
    int* __restrict__ cnt, float* __restrict__ psum) {
  __shared__ float gws[NEXP * DDIM];      // 32 KB
  __shared__ float pblk[4][NEXP];
  __shared__ int cblk[NEXP];
  const int t = threadIdx.x;
  for (int i = t; i < NEXP * DDIM; i += 256) gws[i] = gw[i];
  if (t < NEXP) cblk[t] = 0;
  __syncthreads();
  const int wv = t >> 6, lane = t & 63;
  const int tok = blockIdx.x * 4 + wv;
  double acc[NEXP];
#pragma unroll
  for (int e = 0; e < NEXP; e++) acc[e] = 0.0;
  const float* xr = x + (size_t)tok * DDIM;
  for (int i = lane; i < DDIM; i += 64) {
    double xv = (double)xr[i];
#pragma unroll
    for (int e = 0; e < NEXP; e++) acc[e] += xv * (double)gws[e * DDIM + i];
  }
#pragma unroll
  for (int e = 0; e < NEXP; e++)
    for (int off = 32; off > 0; off >>= 1) acc[e] += __shfl_xor(acc[e], off, 64);
  if (lane == 0) {
    double mx = acc[0];
    for (int e = 1; e < NEXP; e++) mx = acc[e] > mx ? acc[e] : mx;
    double p[NEXP], s = 0.0;
    for (int e = 0; e < NEXP; e++) { p[e] = exp(acc[e] - mx); s += p[e]; }
    int e1 = 0; double b1 = p[0];
    for (int e = 1; e < NEXP; e++) if (p[e] > b1) { b1 = p[e]; e1 = e; }
    int e2 = -1; double b2 = -1.0;
    for (int e = 0; e < NEXP; e++) if (e != e1 && p[e] > b2) { b2 = p[e]; e2 = e; }
    double rs = b1 + b2;
    selE[tok * 2 + 0] = e1; selE[tok * 2 + 1] = e2;
    selW[tok * 2 + 0] = (float)(b1 / rs); selW[tok * 2 + 1] = (float)(b2 / rs);
    atomicAdd(&cblk[e1], 1); atomicAdd(&cblk[e2], 1);
    for (int e = 0; e < NEXP; e++) pblk[wv][e] = (float)(p[e] / s);
  }
  __syncthreads();
  if (t < NEXP) {
    float sp = pblk[0][t] + pblk[1][t] + pblk[2][t] + pblk[3][t];
    atomicAdd(&psum[t], sp);
    if (cblk[t]) atomicAdd(&cnt[t], cblk[t]);
  }
}

// ---------------- prefix sums (256-aligned) + tile->expert table + balance loss ----------------
__global__ __launch_bounds__(256) void finalize_kernel(
    const int* __restrict__ cnt, const float* __restrict__ psum,
    int* __restrict__ abase, int* __restrict__ fill,
    int* __restrict__ tile2exp, float* __restrict__ loss_out) {
  __shared__ int sb[NEXP + 1];
  __shared__ int scnt[NEXP];
  const int t = threadIdx.x;
  if (t == 0) {
    int b = 0;
    for (int e = 0; e < NEXP; e++) {
      int c = cnt[e];
      scnt[e] = c; sb[e] = b;
      b += ((c + 255) >> 8) << 8;
    }
    sb[NEXP] = b;
  }
  __syncthreads();
  if (t < NEXP) { abase[t] = sb[t]; fill[t] = sb[t]; }
  if (t == NEXP) abase[NEXP] = sb[NEXP];
  for (int i = t; i < NMT; i += 256) {
    int ex = -1;
#pragma unroll
    for (int e = 0; e < NEXP; e++) {
      int t0 = sb[e] >> 8, nt = (scnt[e] + 255) >> 8;
      if (i >= t0 && i < t0 + nt) ex = e;
    }
    tile2exp[i] = ex;
  }
  if (t == 0) {
    double L = 0.0;
    for (int e = 0; e < NEXP; e++) L += (double)psum[e] * (double)scnt[e];
    *loss_out = (float)(L * (double)NEXP / ((double)NTOK * (double)NTOK));
  }
}

// ---------------- scatter pairs: block-local histogram -> 1 global atomic per expert ----------------
__global__ __launch_bounds__(256) void scatter_kernel(
    const int* __restrict__ selE, const float* __restrict__ selW,
    int* __restrict__ fill, int* __restrict__ pairtok, float* __restrict__ pairw) {
  __shared__ int h1[NEXP], h2[NEXP], base[NEXP];
  const int t = threadIdx.x;
  if (t < NEXP) { h1[t] = 0; h2[t] = 0; }
  __syncthreads();
  const int n = blockIdx.x * 256 + t;
  const int e0 = selE[n * 2 + 0], e1 = selE[n * 2 + 1];
  atomicAdd(&h1[e0], 1); atomicAdd(&h1[e1], 1);
  __syncthreads();
  if (t < NEXP && h1[t]) base[t] = atomicAdd(&fill[t], h1[t]);
  __syncthreads();
  int r0 = atomicAdd(&h2[e0], 1);
  int p0 = base[e0] + r0;
  pairtok[p0] = n; pairw[p0] = selW[n * 2 + 0];
  int r1 = atomicAdd(&h2[e1], 1);
  int p1 = base[e1] + r1;
  pairtok[p1] = n; pairw[p1] = selW[n * 2 + 1];
}

// ---------------- MFMA GEMM, 256x256 tile, 8-phase-granularity ring-4 pipeline ----------------
// BM=BN=256, BK=32. 512 threads / 8 waves (2M x 4N), per-wave 128x64 output.
// LDS: ring of 4 tile-slots (A 16KB + B 16KB each) = 128 KB.
// While computing tile kt (2 phases x 16 MFMA), stage tile kt+3 -> 3-tile (~6-phase,
// >900cy) prefetch distance. Boundary wait = counted s_waitcnt vmcnt(8) (tiles kt+2,
// kt+3 = 8 loads stay in flight ACROSS barriers; never 0 in steady state) + raw
// s_barrier (no __syncthreads -> no drain). Slot safety: read slot kt&3, write slot
// (kt+3)&3, mod-4 distinct; overwrite of slot s is barrier-separated from its last read.
// MODE 0: FC1  A = xb gathered via pairtok, epilogue relu^2 -> hbuf bf16
// MODE 1: FC2  A = hbuf rows, k-window blockIdx.z*KLEN (split-K), atomicAdd w*y into out
template <int KLEN, int KROW, int ND, int MODE>
__global__ __launch_bounds__(512, 2) void moe_gemm(
    const unsigned short* __restrict__ A, const unsigned short* __restrict__ B,
    const int* __restrict__ abase, const int* __restrict__ cnt,
    const int* __restrict__ tile2exp, const int* __restrict__ pairtok,
    const float* __restrict__ pairw, unsigned short* __restrict__ hbuf,
    float* __restrict__ out) {
  constexpr int NT = ND / 256;
  constexpr int KT = KLEN / 32;

  // XCD-chunked bijective swizzle (m204) over (x,y); z (split-K) independent.
  const int nwg = NT * NMT;
  const int lid = blockIdx.y * NT + blockIdx.x;
  const int q8 = nwg >> 3, r8 = nwg & 7;
  const int xcd = lid & 7, sub = lid >> 3;
  const int cbase = (xcd < r8) ? xcd * (q8 + 1) : r8 * (q8 + 1) + (xcd - r8) * q8;
  const int nlid = cbase + sub;
  const int mtile = nlid / NT;
  const int ntile = nlid - mtile * NT;

  const int e = tile2exp[mtile];
  if (e < 0) return;
  const int m0 = abase[e];
  const int cntE = cnt[e];
  const int mloc = mtile * 256 - m0;
  const int koff = blockIdx.z * KLEN;

  __shared__ unsigned short lds[4][2][8192];   // 4 slots x {A,B} x (256 rows x 32 k) = 128 KB

  const int t = threadIdx.x, w = t >> 6, lane = t & 63;

  // staging: loads i=0,1 -> A chunks i*512+t ; i=2,3 -> B chunks (i-2)*512+t
  // chunk c holds (row=c>>2, q=(c&3)^swz(row)); LDS dest linear, source pre-swizzled.
  const unsigned short* gsrc[4];
  int dchunk[4];
#pragma unroll
  for (int i = 0; i < 4; i++) {
    const int c = (i & 1) * 512 + t;
    const int row = c >> 2;
    const int q = (c & 3) ^ (row & 3) ^ ((row >> 2) & 3);
    dchunk[i] = (i & 1) * 512 + w * 64;        // wave-uniform chunk base
    if (i < 2) {
      int ar = mloc + row;
      if (ar > cntE - 1) ar = cntE - 1;        // clamp tail rows
      size_t arow = (MODE == 0) ? (size_t)pairtok[m0 + ar] : (size_t)(m0 + ar);
      gsrc[i] = A + arow * (size_t)KROW + koff + q * 8;
    } else {
      gsrc[i] = B + ((size_t)e * ND + (ntile * 256 + row)) * (size_t)KROW + koff + q * 8;
    }
  }

  // fragment read positions (short8 units within one slot's operand region)
  const int wr = w >> 2, wc = w & 3;           // 2M x 4N wave grid
  const int sw = (lane >> 4) ^ (lane & 3) ^ ((lane >> 2) & 3);
  int aoff[8], boff[4];
#pragma unroll
  for (int i = 0; i < 8; i++) aoff[i] = (wr * 128 + i * 16 + (lane & 15)) * 4 + sw;
#pragma unroll
  for (int i = 0; i < 4; i++) boff[i] = (wc * 64 + i * 16 + (lane & 15)) * 4 + sw;

  floatx4 acc[8][4] = {};

  // prologue: stage tiles 0,1,2 (12 loads); wait so tile 0 landed (8 newest in flight)
#pragma unroll
  for (int p = 0; p < 3; ++p) {
    unsigned short* d0 = &lds[p][0][0];
    unsigned short* d1 = &lds[p][1][0];
    async_copy16(gsrc[0] + p * 32, d0 + dchunk[0] * 8);
    async_copy16(gsrc[1] + p * 32, d0 + dchunk[1] * 8);
    async_copy16(gsrc[2] + p * 32, d1 + dchunk[2] * 8);
    async_copy16(gsrc[3] + p * 32, d1 + dchunk[3] * 8);
  }
  asm volatile("s_waitcnt vmcnt(8)" ::: "memory");
  __builtin_amdgcn_s_barrier();

  auto tile = [&](int kt, int vmw) __attribute__((always_inline)) {
    const int s_ = kt & 3;
    const short8* LA = (const short8*)(&lds[s_][0][0]);
    const short8* LB = (const short8*)(&lds[s_][1][0]);
    // ---- phase 0: ds-read half the A-frags + all B-frags; stage A of tile kt+3
    short8 af[4], bf[4];
#pragma unroll
    for (int i = 0; i < 4; i++) { af[i] = LA[aoff[i]]; bf[i] = LB[boff[i]]; }
    if (kt + 3 < KT) {
      unsigned short* d = &lds[(kt + 3) & 3][0][0];
      async_copy16(gsrc[0] + (kt + 3) * 32, d + dchunk[0] * 8);
      async_copy16(gsrc[1] + (kt + 3) * 32, d + dchunk[1] * 8);
    }
    __builtin_amdgcn_s_barrier();
    asm volatile("s_waitcnt lgkmcnt(0)" ::: "memory");
    __builtin_amdgcn_s_setprio(1);
#pragma unroll
    for (int mi = 0; mi < 4; mi++)
#pragma unroll
      for (int ni = 0; ni < 4; ni++)
        acc[mi][ni] = __builtin_amdgcn_mfma_f32_16x16x32_bf16(af[mi], bf[ni], acc[mi][ni], 0, 0, 0);
    __builtin_amdgcn_s_setprio(0);
    __builtin_amdgcn_s_barrier();
    // ---- phase 1: ds-read other A-frags (B reused in regs); stage B of tile kt+3
    short8 ag[4];
#pragma unroll
    for (int i = 0; i < 4; i++) ag[i] = LA[aoff[4 + i]];
    if (kt + 3 < KT) {
      unsigned short* d = &lds[(kt + 3) & 3][1][0];
      async_copy16(gsrc[2] + (kt + 3) * 32, d + dchunk[2] * 8);
      async_copy16(gsrc[3] + (kt + 3) * 32, d + dchunk[3] * 8);
    }
    __builtin_amdgcn_s_barrier();
    asm volatile("s_waitcnt lgkmcnt(0)" ::: "memory");
    __builtin_amdgcn_s_setprio(1);
#pragma unroll
    for (int mi = 0; mi < 4; mi++)
#pragma unroll
      for (int ni = 0; ni < 4; ni++)
        acc[4 + mi][ni] = __builtin_amdgcn_mfma_f32_16x16x32_bf16(ag[mi], bf[ni], acc[4 + mi][ni], 0, 0, 0);
    __builtin_amdgcn_s_setprio(0);
    // boundary: tile kt+1 must be fully landed; tiles kt+2, kt+3 (8 loads) stay out
    if (vmw == 8)      asm volatile("s_waitcnt vmcnt(8)" ::: "memory");
    else if (vmw == 4) asm volatile("s_waitcnt vmcnt(4)" ::: "memory");
    else if (vmw == 0) asm volatile("s_waitcnt vmcnt(0)" ::: "memory");
    __builtin_amdgcn_s_barrier();
  };

  for (int kt = 0; kt < KT - 3; ++kt) tile(kt, 8);
  tile(KT - 3, 4);
  tile(KT - 2, 0);
  tile(KT - 1, -1);

  // epilogue: C/D layout row=(lane>>4)*4+r, col=lane&15 (m89/m91-verified)
  const int Mv = cntE - mloc;
  const int colb = ntile * 256 + wc * 64 + (lane & 15);
  const int rowb = wr * 128 + ((lane >> 4) << 2);
#pragma unroll
  for (int mi = 0; mi < 8; mi++) {
#pragma unroll
    for (int r = 0; r < 4; r++) {
      const int rl = rowb + mi * 16 + r;
      if (rl < Mv) {
        const int pr = m0 + mloc + rl;
        if (MODE == 0) {
          unsigned short* hrow = hbuf + (size_t)pr * HDIM + colb;
#pragma unroll
          for (int ni = 0; ni < 4; ni++) {
            float v = acc[mi][ni][r];
            v = v > 0.f ? v * v : 0.f;   // relu^2
            hrow[ni * 16] = f2bf(v);
          }
        } else {
          const float wgt = pairw[pr];
          float* yrow = out + (size_t)pairtok[pr] * DDIM + colb;
#pragma unroll
          for (int ni = 0; ni < 4; ni++)
            atomicAdd(yrow + ni * 16, wgt * acc[mi][ni][r]);
        }
      }
    }
  }
}

extern "C" void kernel_launch(void* const* d_in, const int* in_sizes, int n_in,
                              void* d_out, int out_size, void* d_ws, size_t ws_size,
                              hipStream_t stream) {
  const float* x   = (const float*)d_in[0];
  const float* gw  = (const float*)d_in[1];
  const float* wfc = (const float*)d_in[2];
  const float* wpj = (const float*)d_in[3];
  float* out = (float*)d_out;

  char* ws = (char*)d_ws;
  size_t off = 0;
  auto alloc = [&](size_t bytes) -> void* {
    void* p = ws + off;
    off += (bytes + 255) & ~(size_t)255;
    return p;
  };
  unsigned short* xb   = (unsigned short*)alloc((size_t)NTOK * DDIM * 2);
  unsigned short* wfcb = (unsigned short*)alloc((size_t)NEXP * HDIM * DDIM * 2);
  unsigned short* wpjb = (unsigned short*)alloc((size_t)NEXP * DDIM * HDIM * 2);
  unsigned short* hbuf = (unsigned short*)alloc((size_t)NPADROW * HDIM * 2);
  int*   pairtok = (int*)alloc(NPADROW * 4);
  float* pairw   = (float*)alloc(NPADROW * 4);
  int*   selE    = (int*)alloc(NTOK * 2 * 4);
  float* selW    = (float*)alloc(NTOK * 2 * 4);
  int*   ctr     = (int*)alloc(1024);
  int* cnt = ctr; int* fill = ctr + 8; int* abase = ctr + 16;   // abase: 9 ints
  float* psum = (float*)(ctr + 28);                              // 8 floats
  int* tile2exp = ctr + 40;                                      // 72 ints

  hipMemsetAsync(ctr, 0, 1024, stream);
  hipMemsetAsync(out, 0, (size_t)NTOK * DDIM * 4, stream);       // FC2 accumulates into out

  cast_kernel<<<(NTOK * DDIM / 4 + 255) / 256, 256, 0, stream>>>(x, xb, NTOK * DDIM / 4);
  cast_kernel<<<(NEXP * HDIM * DDIM / 4 + 255) / 256, 256, 0, stream>>>(wfc, wfcb, NEXP * HDIM * DDIM / 4);
  cast_kernel<<<(NEXP * DDIM * HDIM / 4 + 255) / 256, 256, 0, stream>>>(wpj, wpjb, NEXP * DDIM * HDIM / 4);

  gating_kernel<<<NTOK / 4, 256, 0, stream>>>(x, gw, selE, selW, cnt, psum);
  finalize_kernel<<<1, 256, 0, stream>>>(cnt, psum, abase, fill, tile2exp,
                                         out + (size_t)NTOK * DDIM);
  scatter_kernel<<<NTOK / 256, 256, 0, stream>>>(selE, selW, fill, pairtok, pairw);

  // FC1: M(padded) x 4096, K=1024
  moe_gemm<1024, 1024, HDIM, 0><<<dim3(HDIM / 256, NMT, 1), 512, 0, stream>>>(
      xb, wfcb, abase, cnt, tile2exp, pairtok, pairw, hbuf, nullptr);
  // FC2: M(padded) x 1024, K=4096 split 4 ways (atomic accumulate into out)
  moe_gemm<1024, 4096, DDIM, 1><<<dim3(DDIM / 256, NMT, 4), 512, 0, stream>>>(
      hbuf, wpjb, abase, cnt, tile2exp, pairtok, pairw, nullptr, out);
}